// Round 4
// baseline (789.120 us; speedup 1.0000x reference)
//
#include <hip/hip_runtime.h>
#include <hip/hip_bf16.h>
#include <cstdint>

// Shapes: B=512, S=196, I=2048, Q=1024, H=512
// ques_attn == ques_feat exactly (softmax over singleton axis). Only img_attn computed:
//   cc[b][h]  = sum_q qf[b][q]*w2g[q][h] + b2g[h] + b2x[h]
//   score[r]  = sum_h tanh( sum_k X[r][k]*w2x[k][h] + cc[b(r)][h] ) * w2h[h]   (r = b*196+s)
//   a = softmax_s(score);  img_attn[b][f] = sum_s a[b][s] * X[b][s][f]

typedef __attribute__((ext_vector_type(8))) short bf16x8;
typedef __attribute__((ext_vector_type(4))) float f32x4;

__device__ inline unsigned short f2bf(float f) {
    union { float f; unsigned u; } v; v.f = f;
    unsigned u = v.u;
    u += 0x7FFFu + ((u >> 16) & 1u);
    return (unsigned short)(u >> 16);
}

__device__ inline unsigned pk2(float lo, float hi) {
    __hip_bfloat162 h = __float22bfloat162_rn(make_float2(lo, hi));
    return *reinterpret_cast<unsigned*>(&h);
}

// ---------------- out0 = ques_feat (exact copy) ----------------
__global__ void k_copy(const float* __restrict__ src, float* __restrict__ dst) {
    int i = blockIdx.x * blockDim.x + threadIdx.x;
    reinterpret_cast<float4*>(dst)[i] = reinterpret_cast<const float4*>(src)[i];
}

// ---------------- WTf: fragment-major packed bf16 of w2x^T ----------------
// Tile (kblk, nblk) = 64 k x 16 cols: [kc8 0..7][col 0..15][j 0..7];
// a wave's B-fragment read (16 cols x 32 k) is one contiguous 1 KB access.
__global__ void k_pack_w(const float* __restrict__ w, unsigned short* __restrict__ wtf) {
    int kblk = blockIdx.x >> 5;
    int nblk = blockIdx.x & 31;
    int t = threadIdx.x;          // 128: (kc8, col)
    int kc8 = t >> 4, col = t & 15;
    const float* src = w + (size_t)(kblk * 64 + kc8 * 8) * 512 + nblk * 16 + col;
    unsigned short* dst = wtf + (size_t)(kblk * 32 + nblk) * 1024 + kc8 * 128 + col * 8;
    unsigned short tmp[8];
    #pragma unroll
    for (int j = 0; j < 8; ++j) tmp[j] = f2bf(src[(size_t)j * 512]);
    *reinterpret_cast<uint4*>(dst) = *reinterpret_cast<const uint4*>(tmp);
}

// ---------------- cc[b][h] = qf[b]·w2g[:,h] + b2g[h] + b2x[h] ----------------
__global__ void k_cconst(const float* __restrict__ qf, const float* __restrict__ w2g,
                         const float* __restrict__ b2g, const float* __restrict__ b2x,
                         float* __restrict__ cc) {
    __shared__ float qls[2][1024];
    int b0 = blockIdx.x * 2;
    int t = threadIdx.x;
    #pragma unroll
    for (int j = 0; j < 2; ++j) {
        int idx = j * 256 + t;
        int bb = idx >> 8, c4 = idx & 255;
        float4 v = reinterpret_cast<const float4*>(qf + (size_t)(b0 + bb) * 1024)[c4];
        qls[bb][c4 * 4 + 0] = v.x; qls[bb][c4 * 4 + 1] = v.y;
        qls[bb][c4 * 4 + 2] = v.z; qls[bb][c4 * 4 + 3] = v.w;
    }
    __syncthreads();
    float a00 = 0.f, a01 = 0.f, a10 = 0.f, a11 = 0.f;
    #pragma unroll 8
    for (int q = 0; q < 1024; ++q) {
        float w0 = w2g[q * 512 + t];
        float w1 = w2g[q * 512 + 256 + t];
        float q0 = qls[0][q], q1 = qls[1][q];
        a00 += q0 * w0; a01 += q0 * w1;
        a10 += q1 * w0; a11 += q1 * w1;
    }
    float c0 = b2g[t] + b2x[t];
    float c1 = b2g[t + 256] + b2x[t + 256];
    cc[(size_t)b0 * 512 + t] = a00 + c0;
    cc[(size_t)b0 * 512 + t + 256] = a01 + c1;
    cc[(size_t)(b0 + 1) * 512 + t] = a10 + c0;
    cc[(size_t)(b0 + 1) * 512 + t + 256] = a11 + c1;
}

// ---------------- scores: fused GEMM + tanh + dot(w2h) ----------------
// grid 1568 = M-tiles of 64 rows (100352 = 1568*64 exactly); block 512 = 8 waves,
// wave owns 64 cols -> acc 4x4 f32x4 = 64/lane. K-step 64, A LDS dbuf + XOR swizzle,
// 2-step X reg prefetch, B per-kh contiguous 1KB frags from packed WTf (L2-hot).
// __launch_bounds__(512,4): cap regs at 128/wave -> 2 blocks/CU for barrier overlap.
#define NSTEP 32

__global__ __launch_bounds__(512, 4) void k_scores(
    const float* __restrict__ X, const unsigned short* __restrict__ WTf,
    const float* __restrict__ cc, const float* __restrict__ w2h,
    float* __restrict__ scores)
{
    __shared__ __align__(16) unsigned short A[2][64 * 64];
    __shared__ float slds[64];

    int tile = blockIdx.x;
    int tid = threadIdx.x;
    int wave = tid >> 6, lane = tid & 63;
    int l15 = lane & 15, l4 = lane >> 4;

    int r0 = tile * 64;
    int b0 = r0 / 196;
    int sbreak = (b0 + 1) * 196 - r0;   // rows [0,sbreak) belong to b0
    int b1 = b0 + 1; if (b1 > 511) b1 = 511;

    // staging coords: one 32B X chunk per thread per step
    int srow = tid >> 3, sc8 = tid & 7;
    const float* xsrc = X + (size_t)(r0 + srow) * 2048 + sc8 * 8;
    int sbyte = srow * 128 + ((sc8 * 16) ^ ((srow & 7) << 4));

    float cch0[4], cch1[4], whv[4];
    #pragma unroll
    for (int n = 0; n < 4; ++n) {
        int h = wave * 64 + n * 16 + l15;
        cch0[n] = cc[(size_t)b0 * 512 + h];
        cch1[n] = cc[(size_t)b1 * 512 + h];
        whv[n] = w2h[h];
    }

    if (tid < 64) slds[tid] = 0.0f;

    f32x4 acc[4][4];
    #pragma unroll
    for (int m = 0; m < 4; ++m)
        #pragma unroll
        for (int n = 0; n < 4; ++n) acc[m][n] = (f32x4){0.f, 0.f, 0.f, 0.f};

    float4 xa0, xa1, xb0, xb1;

    #define XLOAD(dst0, dst1, t) do { \
        dst0 = *reinterpret_cast<const float4*>(xsrc + (t) * 64); \
        dst1 = *reinterpret_cast<const float4*>(xsrc + (t) * 64 + 4); } while (0)

    #define STAGE(t, v0, v1) do { \
        uint4 o; \
        o.x = pk2(v0.x, v0.y); o.y = pk2(v0.z, v0.w); \
        o.z = pk2(v1.x, v1.y); o.w = pk2(v1.z, v1.w); \
        *reinterpret_cast<uint4*>(reinterpret_cast<char*>(A[(t) & 1]) + sbyte) = o; } while (0)

    #define COMPUTE(t) do { \
        const unsigned short* base = WTf + (size_t)(t) * 32768 + (size_t)wave * 4096; \
        _Pragma("unroll") \
        for (int kh = 0; kh < 2; ++kh) { \
            bf16x8 br[4]; \
            _Pragma("unroll") \
            for (int n = 0; n < 4; ++n) \
                br[n] = *reinterpret_cast<const bf16x8*>(base + n * 1024 + (kh * 4 + l4) * 128 + l15 * 8); \
            __builtin_amdgcn_s_setprio(1); \
            _Pragma("unroll") \
            for (int m = 0; m < 4; ++m) { \
                int abyte = (m * 16 + l15) * 128 + (((kh * 64 + l4 * 16)) ^ ((l15 & 7) << 4)); \
                bf16x8 af = *reinterpret_cast<const bf16x8*>( \
                    reinterpret_cast<const char*>(A[(t) & 1]) + abyte); \
                _Pragma("unroll") \
                for (int n = 0; n < 4; ++n) \
                    acc[m][n] = __builtin_amdgcn_mfma_f32_16x16x32_bf16(af, br[n], acc[m][n], 0, 0, 0); \
            } \
            __builtin_amdgcn_s_setprio(0); \
        } } while (0)

    // prologue
    XLOAD(xa0, xa1, 0);
    XLOAD(xb0, xb1, 1);
    STAGE(0, xa0, xa1);
    __syncthreads();

    #pragma unroll 1
    for (int t2 = 0; t2 < NSTEP; t2 += 2) {
        if (t2 + 2 < NSTEP) XLOAD(xa0, xa1, t2 + 2);
        COMPUTE(t2);
        STAGE(t2 + 1, xb0, xb1);
        __syncthreads();
        if (t2 + 3 < NSTEP) XLOAD(xb0, xb1, t2 + 3);
        COMPUTE(t2 + 1);
        if (t2 + 2 < NSTEP) { STAGE(t2 + 2, xa0, xa1); __syncthreads(); }
    }

    // epilogue: score[row] = sum_h tanh(feat + cc[b(row)][h]) * w2h[h]
    #pragma unroll
    for (int m = 0; m < 4; ++m) {
        #pragma unroll
        for (int i = 0; i < 4; ++i) {
            int row = m * 16 + l4 * 4 + i;
            float p = 0.0f;
            #pragma unroll
            for (int n = 0; n < 4; ++n) {
                float x = acc[m][n][i] + ((row < sbreak) ? cch0[n] : cch1[n]);
                float th = 1.0f - 2.0f / (__expf(2.0f * x) + 1.0f);
                p += th * whv[n];
            }
            p += __shfl_xor(p, 1);
            p += __shfl_xor(p, 2);
            p += __shfl_xor(p, 4);
            p += __shfl_xor(p, 8);
            if (l15 == 0) atomicAdd(&slds[row], p);
        }
    }
    __syncthreads();
    if (tid < 64) scores[(size_t)r0 + tid] = slds[tid];
}

// ---------------- softmax over s (196) per b ----------------
__global__ void k_softmax(float* sc) {
    int b = blockIdx.x, t = threadIdx.x;
    __shared__ float red[8];
    float v = (t < 196) ? sc[(size_t)b * 196 + t] : -3.0e38f;
    float m = v;
    for (int o = 32; o > 0; o >>= 1) m = fmaxf(m, __shfl_xor(m, o));
    if ((t & 63) == 0) red[t >> 6] = m;
    __syncthreads();
    m = fmaxf(fmaxf(red[0], red[1]), fmaxf(red[2], red[3]));
    float e = (t < 196) ? __expf(v - m) : 0.0f;
    float s = e;
    for (int o = 32; o > 0; o >>= 1) s += __shfl_xor(s, o);
    if ((t & 63) == 0) red[4 + (t >> 6)] = s;
    __syncthreads();
    float tot = red[4] + red[5] + red[6] + red[7];
    if (t < 196) sc[(size_t)b * 196 + t] = e / tot;
}

// ---------------- img_attn[b][f] = sum_s a[b][s] * X[b][s][f] ----------------
__global__ void k_wsum(const float* __restrict__ X, const float* __restrict__ a,
                       float* __restrict__ out1) {
    __shared__ float als[196];
    int b = blockIdx.x >> 1;
    int fh = (blockIdx.x & 1) * 1024;
    int t = threadIdx.x;
    if (t < 196) als[t] = a[(size_t)b * 196 + t];
    __syncthreads();
    int f = fh + t * 4;
    const float* Xb = X + (size_t)b * 196 * 2048 + f;
    float4 acc = {0.f, 0.f, 0.f, 0.f};
    #pragma unroll 4
    for (int s = 0; s < 196; ++s) {
        float4 x = *reinterpret_cast<const float4*>(Xb + (size_t)s * 2048);
        float w = als[s];
        acc.x += w * x.x; acc.y += w * x.y; acc.z += w * x.z; acc.w += w * x.w;
    }
    *reinterpret_cast<float4*>(out1 + (size_t)b * 2048 + f) = acc;
}

extern "C" void kernel_launch(void* const* d_in, const int* in_sizes, int n_in,
                              void* d_out, int out_size, void* d_ws, size_t ws_size,
                              hipStream_t stream) {
    const float* qf  = (const float*)d_in[0];
    const float* X   = (const float*)d_in[1];
    const float* w2x = (const float*)d_in[6];
    const float* b2x = (const float*)d_in[7];
    const float* w2g = (const float*)d_in[8];
    const float* b2g = (const float*)d_in[9];
    const float* w2h = (const float*)d_in[10];

    float* out0 = (float*)d_out;                 // ques_attn = ques_feat (512x1024)
    float* out1 = out0 + 512 * 1024;             // img_attn (512x2048)

    // ws layout: [0,2MB) WTf bf16 packed; [2MB,3MB) cc f32; [3MB,..) scores f32 flat [100352]
    unsigned short* WTf = (unsigned short*)d_ws;
    float* cc = (float*)((char*)d_ws + (size_t)(2u << 20));
    float* sc = (float*)((char*)d_ws + (size_t)(3u << 20));

    k_copy<<<512, 256, 0, stream>>>(qf, out0);
    k_pack_w<<<1024, 128, 0, stream>>>(w2x, WTf);
    k_cconst<<<256, 256, 0, stream>>>(qf, w2g, b2g, b2x, cc);
    k_scores<<<1568, 512, 0, stream>>>(X, WTf, cc, w2h, sc);
    k_softmax<<<512, 256, 0, stream>>>(sc);
    k_wsum<<<1024, 256, 0, stream>>>(X, sc, out1);
}

// Round 5
// 660.346 us; speedup vs baseline: 1.1950x; 1.1950x over previous
//
#include <hip/hip_runtime.h>
#include <hip/hip_bf16.h>
#include <cstdint>

// Shapes: B=512, S=196, I=2048, Q=1024, H=512
// ques_attn == ques_feat exactly (softmax over singleton axis). Only img_attn computed:
//   cc[b][h]  = sum_q qf[b][q]*w2g[q][h] + b2g[h] + b2x[h]
//   score[r]  = sum_h tanh( sum_k X[r][k]*w2x[k][h] + cc[b(r)][h] ) * w2h[h]   (r = b*196+s)
//   a = softmax_s(score);  img_attn[b][f] = sum_s a[b][s] * X[b][s][f]

typedef __attribute__((ext_vector_type(8))) short bf16x8;
typedef __attribute__((ext_vector_type(4))) float f32x4;

__device__ inline unsigned short f2bf(float f) {
    union { float f; unsigned u; } v; v.f = f;
    unsigned u = v.u;
    u += 0x7FFFu + ((u >> 16) & 1u);
    return (unsigned short)(u >> 16);
}

__device__ inline unsigned pk2(float lo, float hi) {
    __hip_bfloat162 h = __float22bfloat162_rn(make_float2(lo, hi));
    return *reinterpret_cast<unsigned*>(&h);
}

// ---------------- out0 = ques_feat (exact copy) ----------------
__global__ void k_copy(const float* __restrict__ src, float* __restrict__ dst) {
    int i = blockIdx.x * blockDim.x + threadIdx.x;
    reinterpret_cast<float4*>(dst)[i] = reinterpret_cast<const float4*>(src)[i];
}

// ---------------- WTf: fragment-major packed bf16 of w2x^T ----------------
// Tile (kblk, nblk) = 64 k x 16 cols: [kc8 0..7][col 0..15][j 0..7];
// a wave's B-fragment read (16 cols x 32 k) is one contiguous 1 KB access.
__global__ void k_pack_w(const float* __restrict__ w, unsigned short* __restrict__ wtf) {
    int kblk = blockIdx.x >> 5;
    int nblk = blockIdx.x & 31;
    int t = threadIdx.x;          // 128: (kc8, col)
    int kc8 = t >> 4, col = t & 15;
    const float* src = w + (size_t)(kblk * 64 + kc8 * 8) * 512 + nblk * 16 + col;
    unsigned short* dst = wtf + (size_t)(kblk * 32 + nblk) * 1024 + kc8 * 128 + col * 8;
    unsigned short tmp[8];
    #pragma unroll
    for (int j = 0; j < 8; ++j) tmp[j] = f2bf(src[(size_t)j * 512]);
    *reinterpret_cast<uint4*>(dst) = *reinterpret_cast<const uint4*>(tmp);
}

// ---------------- cc[b][h] = qf[b]·w2g[:,h] + b2g[h] + b2x[h] ----------------
__global__ void k_cconst(const float* __restrict__ qf, const float* __restrict__ w2g,
                         const float* __restrict__ b2g, const float* __restrict__ b2x,
                         float* __restrict__ cc) {
    __shared__ float qls[2][1024];
    int b0 = blockIdx.x * 2;
    int t = threadIdx.x;
    #pragma unroll
    for (int j = 0; j < 2; ++j) {
        int idx = j * 256 + t;
        int bb = idx >> 8, c4 = idx & 255;
        float4 v = reinterpret_cast<const float4*>(qf + (size_t)(b0 + bb) * 1024)[c4];
        qls[bb][c4 * 4 + 0] = v.x; qls[bb][c4 * 4 + 1] = v.y;
        qls[bb][c4 * 4 + 2] = v.z; qls[bb][c4 * 4 + 3] = v.w;
    }
    __syncthreads();
    float a00 = 0.f, a01 = 0.f, a10 = 0.f, a11 = 0.f;
    #pragma unroll 8
    for (int q = 0; q < 1024; ++q) {
        float w0 = w2g[q * 512 + t];
        float w1 = w2g[q * 512 + 256 + t];
        float q0 = qls[0][q], q1 = qls[1][q];
        a00 += q0 * w0; a01 += q0 * w1;
        a10 += q1 * w0; a11 += q1 * w1;
    }
    float c0 = b2g[t] + b2x[t];
    float c1 = b2g[t + 256] + b2x[t + 256];
    cc[(size_t)b0 * 512 + t] = a00 + c0;
    cc[(size_t)b0 * 512 + t + 256] = a01 + c1;
    cc[(size_t)(b0 + 1) * 512 + t] = a10 + c0;
    cc[(size_t)(b0 + 1) * 512 + t + 256] = a11 + c1;
}

// ---------------- scores: fused GEMM + tanh + dot(w2h) ----------------
// grid 1568 M-tiles of 64 rows; block 512 = 8 waves, wave owns 64 cols (acc 64/lane).
// K-step 64, A LDS dbuf + XOR swizzle, 2-step X reg prefetch, B contiguous frags
// from packed WTf (L2-hot). Register-lean: epilogue constants reloaded AFTER the
// K-loop (fence), B/A addressing via single voffset + immediates.
// __launch_bounds__(512,4): 128-reg cap -> 2 blocks/CU. (r4 spilled at this cap:
// 800MB scratch writes; this version holds ~50 arch VGPR + 64 AGPR.)
#define NSTEP 32

__global__ __launch_bounds__(512, 4) void k_scores(
    const float* __restrict__ X, const unsigned short* __restrict__ WTf,
    const float* __restrict__ cc, const float* __restrict__ w2h,
    float* __restrict__ scores)
{
    __shared__ __align__(16) unsigned short A[2][64 * 64];
    __shared__ float slds[64];

    int tid = threadIdx.x;
    int wave = tid >> 6, lane = tid & 63;
    int l15 = lane & 15, l4 = lane >> 4;
    int r0 = blockIdx.x * 64;

    // staging coords: one 32B X chunk per thread per step
    int srow = tid >> 3, sc8 = tid & 7;
    const float* xsrc = X + (size_t)(r0 + srow) * 2048 + sc8 * 8;
    char* abase = reinterpret_cast<char*>(&A[0][0]);
    int sbyte = srow * 128 + ((sc8 * 16) ^ ((srow & 7) << 4));

    // B fragment base: + t*32768 elems per step; (n,kh) offsets are immediates
    const unsigned short* wbase = WTf + (size_t)wave * 4096 + l4 * 128 + l15 * 8;

    // A fragment voffsets for kh=0/1 (XOR folded); + buf*8192 + m*2048 immediates
    int axor = (l15 & 7) << 4;
    int aoff0 = l15 * 128 + ((l4 * 16) ^ axor);
    int aoff1 = l15 * 128 + ((64 + l4 * 16) ^ axor);

    if (tid < 64) slds[tid] = 0.0f;

    f32x4 acc[4][4];
    #pragma unroll
    for (int m = 0; m < 4; ++m)
        #pragma unroll
        for (int n = 0; n < 4; ++n) acc[m][n] = (f32x4){0.f, 0.f, 0.f, 0.f};

    float4 xa0, xa1, xb0, xb1;

    #define XLOAD(d0, d1, t) do { \
        d0 = *reinterpret_cast<const float4*>(xsrc + (t) * 64); \
        d1 = *reinterpret_cast<const float4*>(xsrc + (t) * 64 + 4); } while (0)

    #define STAGE(buf, v0, v1) do { \
        uint4 o; \
        o.x = pk2(v0.x, v0.y); o.y = pk2(v0.z, v0.w); \
        o.z = pk2(v1.x, v1.y); o.w = pk2(v1.z, v1.w); \
        *reinterpret_cast<uint4*>(abase + (buf) * 8192 + sbyte) = o; } while (0)

    #define COMPUTE(t, buf) do { \
        const unsigned short* base = wbase + (size_t)(t) * 32768; \
        _Pragma("unroll") \
        for (int kh = 0; kh < 2; ++kh) { \
            bf16x8 br[4]; \
            _Pragma("unroll") \
            for (int n = 0; n < 4; ++n) \
                br[n] = *reinterpret_cast<const bf16x8*>(base + n * 1024 + kh * 512); \
            int aoffk = kh ? aoff1 : aoff0; \
            __builtin_amdgcn_s_setprio(1); \
            _Pragma("unroll") \
            for (int m = 0; m < 4; ++m) { \
                bf16x8 af = *reinterpret_cast<const bf16x8*>( \
                    abase + (buf) * 8192 + m * 2048 + aoffk); \
                _Pragma("unroll") \
                for (int n = 0; n < 4; ++n) \
                    acc[m][n] = __builtin_amdgcn_mfma_f32_16x16x32_bf16(af, br[n], acc[m][n], 0, 0, 0); \
            } \
            __builtin_amdgcn_s_setprio(0); \
        } } while (0)

    // prologue
    XLOAD(xa0, xa1, 0);
    XLOAD(xb0, xb1, 1);
    STAGE(0, xa0, xa1);
    __syncthreads();

    #pragma unroll 1
    for (int t2 = 0; t2 < NSTEP; t2 += 2) {
        if (t2 + 2 < NSTEP) XLOAD(xa0, xa1, t2 + 2);
        COMPUTE(t2, 0);
        STAGE(1, xb0, xb1);
        __syncthreads();
        if (t2 + 3 < NSTEP) XLOAD(xb0, xb1, t2 + 3);
        COMPUTE(t2 + 1, 1);
        if (t2 + 2 < NSTEP) { STAGE(0, xa0, xa1); __syncthreads(); }
    }

    // fence: keep the epilogue constant loads from being hoisted into the loop
    asm volatile("" ::: "memory");

    // epilogue: score[row] = sum_h tanh(feat + cc[b(row)][h]) * w2h[h]
    int b0 = r0 / 196;
    int sbreak = (b0 + 1) * 196 - r0;
    int b1 = b0 + 1; if (b1 > 511) b1 = 511;
    float cch0[4], cch1[4], whv[4];
    #pragma unroll
    for (int n = 0; n < 4; ++n) {
        int h = wave * 64 + n * 16 + l15;
        cch0[n] = cc[(size_t)b0 * 512 + h];
        cch1[n] = cc[(size_t)b1 * 512 + h];
        whv[n] = w2h[h];
    }
    #pragma unroll
    for (int m = 0; m < 4; ++m) {
        #pragma unroll
        for (int i = 0; i < 4; ++i) {
            int row = m * 16 + l4 * 4 + i;
            float p = 0.0f;
            #pragma unroll
            for (int n = 0; n < 4; ++n) {
                float x = acc[m][n][i] + ((row < sbreak) ? cch0[n] : cch1[n]);
                float th = 1.0f - 2.0f / (__expf(2.0f * x) + 1.0f);
                p += th * whv[n];
            }
            p += __shfl_xor(p, 1);
            p += __shfl_xor(p, 2);
            p += __shfl_xor(p, 4);
            p += __shfl_xor(p, 8);
            if (l15 == 0) atomicAdd(&slds[row], p);
        }
    }
    __syncthreads();
    if (tid < 64) scores[(size_t)r0 + tid] = slds[tid];
}

// ---------------- softmax over s (196) per b ----------------
__global__ void k_softmax(float* sc) {
    int b = blockIdx.x, t = threadIdx.x;
    __shared__ float red[8];
    float v = (t < 196) ? sc[(size_t)b * 196 + t] : -3.0e38f;
    float m = v;
    for (int o = 32; o > 0; o >>= 1) m = fmaxf(m, __shfl_xor(m, o));
    if ((t & 63) == 0) red[t >> 6] = m;
    __syncthreads();
    m = fmaxf(fmaxf(red[0], red[1]), fmaxf(red[2], red[3]));
    float e = (t < 196) ? __expf(v - m) : 0.0f;
    float s = e;
    for (int o = 32; o > 0; o >>= 1) s += __shfl_xor(s, o);
    if ((t & 63) == 0) red[4 + (t >> 6)] = s;
    __syncthreads();
    float tot = red[4] + red[5] + red[6] + red[7];
    if (t < 196) sc[(size_t)b * 196 + t] = e / tot;
}

// ---------------- img_attn[b][f] = sum_s a[b][s] * X[b][s][f] ----------------
__global__ void k_wsum(const float* __restrict__ X, const float* __restrict__ a,
                       float* __restrict__ out1) {
    __shared__ float als[196];
    int b = blockIdx.x >> 1;
    int fh = (blockIdx.x & 1) * 1024;
    int t = threadIdx.x;
    if (t < 196) als[t] = a[(size_t)b * 196 + t];
    __syncthreads();
    int f = fh + t * 4;
    const float* Xb = X + (size_t)b * 196 * 2048 + f;
    float4 acc = {0.f, 0.f, 0.f, 0.f};
    #pragma unroll 4
    for (int s = 0; s < 196; ++s) {
        float4 x = *reinterpret_cast<const float4*>(Xb + (size_t)s * 2048);
        float w = als[s];
        acc.x += w * x.x; acc.y += w * x.y; acc.z += w * x.z; acc.w += w * x.w;
    }
    *reinterpret_cast<float4*>(out1 + (size_t)b * 2048 + f) = acc;
}

extern "C" void kernel_launch(void* const* d_in, const int* in_sizes, int n_in,
                              void* d_out, int out_size, void* d_ws, size_t ws_size,
                              hipStream_t stream) {
    const float* qf  = (const float*)d_in[0];
    const float* X   = (const float*)d_in[1];
    const float* w2x = (const float*)d_in[6];
    const float* b2x = (const float*)d_in[7];
    const float* w2g = (const float*)d_in[8];
    const float* b2g = (const float*)d_in[9];
    const float* w2h = (const float*)d_in[10];

    float* out0 = (float*)d_out;                 // ques_attn = ques_feat (512x1024)
    float* out1 = out0 + 512 * 1024;             // img_attn (512x2048)

    // ws layout: [0,2MB) WTf bf16 packed; [2MB,3MB) cc f32; [3MB,..) scores f32 flat [100352]
    unsigned short* WTf = (unsigned short*)d_ws;
    float* cc = (float*)((char*)d_ws + (size_t)(2u << 20));
    float* sc = (float*)((char*)d_ws + (size_t)(3u << 20));

    k_copy<<<512, 256, 0, stream>>>(qf, out0);
    k_pack_w<<<1024, 128, 0, stream>>>(w2x, WTf);
    k_cconst<<<256, 256, 0, stream>>>(qf, w2g, b2g, b2x, cc);
    k_scores<<<1568, 512, 0, stream>>>(X, WTf, cc, w2h, sc);
    k_softmax<<<512, 256, 0, stream>>>(sc);
    k_wsum<<<1024, 256, 0, stream>>>(X, sc, out1);
}